// Round 6
// baseline (221.142 us; speedup 1.0000x reference)
//
#include <hip/hip_runtime.h>

typedef unsigned short u16;
typedef unsigned int u32;
typedef __attribute__((ext_vector_type(8))) short short8;
typedef __attribute__((ext_vector_type(4))) float f32x4;

#define MFMA16(a, b, c) __builtin_amdgcn_mfma_f32_16x16x32_bf16(a, b, c, 0, 0, 0)

// B=2, S=2048, D=1024, H=16, KVH=4, dk=64, G=4
#define SEQ 2048
#define DM 1024

__device__ __forceinline__ u16 f2bf(float f) {
  u32 u = __float_as_uint(f);
  u += 0x7fffu + ((u >> 16) & 1u);  // RNE
  return (u16)(u >> 16);
}
__device__ __forceinline__ u32 pack2(float a, float b) {  // RNE pack
  return (u32)f2bf(a) | ((u32)f2bf(b) << 16);
}
__device__ __forceinline__ u32 pack2t(float a, float b) {  // truncating pack: 1 v_perm
  return __builtin_amdgcn_perm(__float_as_uint(b), __float_as_uint(a), 0x07060302u);
}

// async global -> LDS DMA, 16B per lane, dest = wave-uniform base + lane*16
__device__ __forceinline__ void gl_lds(const u16* g, u16* l) {
  __builtin_amdgcn_global_load_lds(
      (const __attribute__((address_space(1))) unsigned int*)(g),
      (__attribute__((address_space(3))) unsigned int*)(l), 16, 0, 0);
}

// ---------- prep: 3x fp32->bf16 convert + weight transposes into cat WqkvT + WoT ----------
// grid (1024, 7): y<3 converts; y in 3..6 transposes (x = kt*32 + nt)
__global__ void k_prep(const float* __restrict__ qin, const float* __restrict__ kin,
                       const float* __restrict__ vin, const float* __restrict__ Wq,
                       const float* __restrict__ Wk, const float* __restrict__ Wv,
                       const float* __restrict__ Wo, u16* __restrict__ qo,
                       u16* __restrict__ ko, u16* __restrict__ vo,
                       u16* __restrict__ WqkvT, u16* __restrict__ WoT) {
  const int y = blockIdx.y;
  if (y < 3) {
    const float* in = y == 0 ? qin : (y == 1 ? kin : vin);
    u16* out = y == 0 ? qo : (y == 1 ? ko : vo);
    const int n = 2 * SEQ * DM;
    for (int i = (blockIdx.x * 256 + threadIdx.x) * 4; i < n; i += gridDim.x * 256 * 4) {
      float4 f = *(const float4*)(in + i);
      uint2 o;
      o.x = pack2(f.x, f.y);
      o.y = pack2(f.z, f.w);
      *(uint2*)(out + i) = o;
    }
  } else {
    const int z = y - 3;
    const float* W = z == 0 ? Wq : (z == 1 ? Wk : (z == 2 ? Wv : Wo));
    u16* Wt = z == 3 ? WoT : (WqkvT + (z == 0 ? 0 : (z == 1 ? 1024 : 1280)) * 1024);
    const int N = (z == 1 || z == 2) ? 256 : 1024;
    const int nt = blockIdx.x & 31, kt = blockIdx.x >> 5;
    const int n0 = nt * 32;
    if (n0 >= N) return;
    const int k0 = kt * 32;
    __shared__ float tile[32][33];
    int x = threadIdx.x & 31, yy = threadIdx.x >> 5;
#pragma unroll
    for (int i = 0; i < 4; i++)
      tile[yy + i * 8][x] = W[(size_t)(k0 + yy + i * 8) * N + n0 + x];
    __syncthreads();
#pragma unroll
    for (int i = 0; i < 4; i++)
      Wt[(size_t)(n0 + yy + i * 8) * 1024 + k0 + x] = f2bf(tile[x][yy + i * 8]);
  }
}

// ---------- m97-style 128x128 GEMM core, BK=64, global_load_lds staging ----------
// unpadded [row][64] LDS (m97 layout). acc per wave: 4x4 over (wm,wn) 64x64 quadrant.
__device__ __forceinline__ void gemm128(const u16* __restrict__ A, const u16* __restrict__ Bt,
                                        int m0, int n0, u16* lA, u16* lB, f32x4 acc[4][4]) {
  const int tid = threadIdx.x;
  const int lane = tid & 63, wave = tid >> 6;
  const int l15 = lane & 15, quad = lane >> 4;
  const int wm = wave >> 1, wn = wave & 1;
  const int lrow = lane >> 3, lcol = (lane & 7) * 8;  // within-chunk mapping (lane*16B)
  f32x4 zero = {0.f, 0.f, 0.f, 0.f};
#pragma unroll
  for (int i = 0; i < 4; i++)
#pragma unroll
    for (int j = 0; j < 4; j++) acc[i][j] = zero;

  for (int k0 = 0; k0 < 1024; k0 += 64) {
    // stage 16KB A + 16KB B: 16 chunks each of 1KB; wave w -> chunks w*4..w*4+3
#pragma unroll
    for (int c = 0; c < 4; c++) {
      int ch = wave * 4 + c;
      int row = ch * 8 + lrow;
      gl_lds(A + (size_t)(m0 + row) * 1024 + k0 + lcol, &lA[ch * 512]);
      gl_lds(Bt + (size_t)(n0 + row) * 1024 + k0 + lcol, &lB[ch * 512]);
    }
    __syncthreads();  // vmcnt(0) drain covers the LDS-DMA
    short8 af[4][2], bfr[4][2];
#pragma unroll
    for (int i = 0; i < 4; i++)
#pragma unroll
      for (int kb = 0; kb < 2; kb++) {
        af[i][kb] = *(const short8*)&lA[(wm * 64 + i * 16 + l15) * 64 + kb * 32 + quad * 8];
        bfr[i][kb] = *(const short8*)&lB[(wn * 64 + i * 16 + l15) * 64 + kb * 32 + quad * 8];
      }
#pragma unroll
    for (int i = 0; i < 4; i++)
#pragma unroll
      for (int j = 0; j < 4; j++) {
        acc[i][j] = MFMA16(af[i][0], bfr[j][0], acc[i][j]);
        acc[i][j] = MFMA16(af[i][1], bfr[j][1], acc[i][j]);
      }
    __syncthreads();
  }
}

// ---------- fused QKV projection: swapped orientation ----------
// A = WqkvT [1536,1024] (cols of output), B = activation tokens [4096,1024].
// grid (12, 32): x = col-tile (0-7 Q, 8-9 K, 10-11 V), y = token-tile.
__global__ __launch_bounds__(256) void k_proj(
    const u16* __restrict__ WqkvT, const u16* __restrict__ qa, const u16* __restrict__ ka,
    const u16* __restrict__ va, const float* __restrict__ bq, const float* __restrict__ bk,
    const float* __restrict__ bv, u16* __restrict__ qbf, float* __restrict__ outK,
    u16* __restrict__ kbf, float* __restrict__ outV, u16* __restrict__ vtb, float qscale) {
  __shared__ u16 lA[128 * 64];
  __shared__ u16 lB[128 * 64];
  const int m0 = blockIdx.x * 128, n0 = blockIdx.y * 128;
  const int mode = m0 < 1024 ? 0 : (m0 < 1280 ? 1 : 2);  // block-uniform region
  const u16* act = mode == 0 ? qa : (mode == 1 ? ka : va);
  const float* bias = mode == 0 ? bq : (mode == 1 ? bk : bv);
  const int cbase = mode == 0 ? 0 : (mode == 1 ? 1024 : 1280);

  f32x4 acc[4][4];
  gemm128(WqkvT, act, m0, n0, lA, lB, acc);

  const int lane = threadIdx.x & 63, wave = threadIdx.x >> 6;
  const int l15 = lane & 15, quad = lane >> 4;
  const int wm = wave >> 1, wn = wave & 1;
#pragma unroll
  for (int i = 0; i < 4; i++) {
    int c0 = m0 + wm * 64 + i * 16 + quad * 4;  // output col (4-aligned)
    int cv = c0 - cbase;
    float4 bb = *(const float4*)(bias + cv);
#pragma unroll
    for (int j = 0; j < 4; j++) {
      int token = n0 + wn * 64 + j * 16 + l15;
      int b = token >> 11, s = token & 2047;
      float v0 = acc[i][j][0] + bb.x, v1 = acc[i][j][1] + bb.y;
      float v2 = acc[i][j][2] + bb.z, v3 = acc[i][j][3] + bb.w;
      if (mode == 0) {
        int h = cv >> 6, d = cv & 63;
        uint2 o;
        o.x = pack2(v0 * qscale, v1 * qscale);
        o.y = pack2(v2 * qscale, v3 * qscale);
        *(uint2*)(qbf + (((size_t)(b * 16 + h) * SEQ + s) << 6) + d) = o;
      } else if (mode == 1) {
        int kvh = cv >> 6, d = cv & 63;
        size_t ix = (((size_t)(b * 4 + kvh) * SEQ + s) << 6) + d;
        float4 vv = {v0, v1, v2, v3};
        *(float4*)(outK + ix) = vv;
        uint2 o;
        o.x = pack2(v0, v1);
        o.y = pack2(v2, v3);
        *(uint2*)(kbf + ix) = o;
      } else {
        int kvh = cv >> 6, d = cv & 63;
        size_t ix = (((size_t)(b * 4 + kvh) * SEQ + s) << 6) + d;
        float4 vv = {v0, v1, v2, v3};
        *(float4*)(outV + ix) = vv;
        // V^T [b,kvh,d,s]: regs are consecutive d -> 4 scalar u16, lanes contiguous in s
        size_t tb = ((size_t)(b * 4 + kvh) * 64 + d) * SEQ + s;
        vtb[tb] = f2bf(v0);
        vtb[tb + SEQ] = f2bf(v1);
        vtb[tb + 2 * SEQ] = f2bf(v2);
        vtb[tb + 3 * SEQ] = f2bf(v3);
      }
    }
  }
}

// ---------- output projection: swapped (A=WoT, B=ctxb), float4 stores ----------
__global__ __launch_bounds__(256) void k_out(const u16* __restrict__ WoT,
                                             const u16* __restrict__ ctxb,
                                             const float* __restrict__ bo,
                                             float* __restrict__ out) {
  __shared__ u16 lA[128 * 64];
  __shared__ u16 lB[128 * 64];
  const int m0 = blockIdx.x * 128, n0 = blockIdx.y * 128;
  f32x4 acc[4][4];
  gemm128(WoT, ctxb, m0, n0, lA, lB, acc);

  const int lane = threadIdx.x & 63, wave = threadIdx.x >> 6;
  const int l15 = lane & 15, quad = lane >> 4;
  const int wm = wave >> 1, wn = wave & 1;
#pragma unroll
  for (int i = 0; i < 4; i++) {
    int c0 = m0 + wm * 64 + i * 16 + quad * 4;
    float4 bb = *(const float4*)(bo + c0);
#pragma unroll
    for (int j = 0; j < 4; j++) {
      int token = n0 + wn * 64 + j * 16 + l15;
      float4 vv = {acc[i][j][0] + bb.x, acc[i][j][1] + bb.y, acc[i][j][2] + bb.z,
                   acc[i][j][3] + bb.w};
      *(float4*)(out + (size_t)token * DM + c0) = vv;
    }
  }
}

// ---------- flash attention: 128-key LDS segments, 2 barrier-free subtiles each ----------
// (unchanged from round 5: 57.6 us, MfmaUtil 27%)
__global__ __launch_bounds__(256, 4) void k_flash(const u16* __restrict__ Qh,
                                                  const u16* __restrict__ Kb,
                                                  const u16* __restrict__ Vt,
                                                  u16* __restrict__ ctx) {
  __shared__ u16 lK[128 * 64];     // [key][d], 8 chunks/row, chunk' = ch ^ (row&7)
  __shared__ u16 lV[64 * 128];     // [d][key], 16 chunks/row, chunk' = ch ^ (row&15)
  __shared__ u16 lP[4 * 16 * 64];  // per-wave [q][key(64)], 8 chunks, ch ^ (q&7)
  const int tid = threadIdx.x;
  const int lane = tid & 63, wave = tid >> 6;
  const int l15 = lane & 15, quad = lane >> 4;
  const int bh = blockIdx.y;
  const int b = bh >> 4, h = bh & 15, kvh = h >> 2;
  const u16* Q = Qh + (size_t)bh * SEQ * 64;
  const u16* Kp = Kb + (size_t)(b * 4 + kvh) * SEQ * 64;
  const u16* Vp = Vt + (size_t)(b * 4 + kvh) * 64 * SEQ;
  const int q0 = blockIdx.x * 64 + wave * 16;

  short8 qf[2];
#pragma unroll
  for (int kb = 0; kb < 2; kb++)
    qf[kb] = *(const short8*)(Q + (size_t)(q0 + l15) * 64 + kb * 32 + quad * 8);

  short8 ones8;
  {
    short ov = (l15 == 0) ? (short)0x3F80 : (short)0;
    ones8 = (short8){ov, ov, ov, ov, ov, ov, ov, ov};
  }

  f32x4 zero = {0.f, 0.f, 0.f, 0.f};
  f32x4 acc[4];
  f32x4 lacc = zero;
#pragma unroll
  for (int n = 0; n < 4; n++) acc[n] = zero;

  u16* lPw = lP + wave * (16 * 64);
  const int t8 = tid * 8;

  for (int kc = 0; kc < SEQ; kc += 128) {
    __syncthreads();
#pragma unroll
    for (int i = 0; i < 4; i++) {
      int e = i * 2048 + t8;
      int row = e >> 6, ch = tid & 7;
      uint4 v = *(const uint4*)(Kp + (size_t)kc * 64 + e);
      *(uint4*)&lK[row * 64 + ((ch ^ (row & 7)) << 3)] = v;
    }
#pragma unroll
    for (int i = 0; i < 4; i++) {
      int e = i * 2048 + t8;
      int row = e >> 7, ch = tid & 15;
      uint4 v = *(const uint4*)(Vp + (size_t)row * SEQ + kc + ch * 8);
      *(uint4*)&lV[row * 128 + ((ch ^ (row & 15)) << 3)] = v;
    }
    __syncthreads();

#pragma unroll
    for (int sub = 0; sub < 2; sub++) {
      const int ks = sub * 64;
      f32x4 sc[4];
#pragma unroll
      for (int mt = 0; mt < 4; mt++) {
        int row = ks + mt * 16 + l15;
        short8 kf0 = *(const short8*)&lK[row * 64 + ((quad ^ (row & 7)) << 3)];
        short8 kf1 = *(const short8*)&lK[row * 64 + (((4 + quad) ^ (row & 7)) << 3)];
        f32x4 t = MFMA16(kf0, qf[0], zero);
        sc[mt] = MFMA16(kf1, qf[1], t);
      }
#pragma unroll
      for (int mt = 0; mt < 4; mt++) {
        float e0 = __builtin_amdgcn_exp2f(sc[mt][0]);
        float e1 = __builtin_amdgcn_exp2f(sc[mt][1]);
        float e2 = __builtin_amdgcn_exp2f(sc[mt][2]);
        float e3 = __builtin_amdgcn_exp2f(sc[mt][3]);
        int chp = mt * 2 + (quad >> 1);
        uint2 p;
        p.x = pack2t(e0, e1);
        p.y = pack2t(e2, e3);
        *(uint2*)&lPw[l15 * 64 + ((chp ^ (l15 & 7)) << 3) + (quad & 1) * 4] = p;
      }
      __asm__ volatile("s_waitcnt lgkmcnt(0)" ::: "memory");
#pragma unroll
      for (int kbp = 0; kbp < 2; kbp++) {
        int chq = kbp * 4 + quad;
        short8 pf = *(const short8*)&lPw[l15 * 64 + ((chq ^ (l15 & 7)) << 3)];
        lacc = MFMA16(ones8, pf, lacc);
#pragma unroll
        for (int n = 0; n < 4; n++) {
          int row = n * 16 + l15;
          int chv = sub * 8 + kbp * 4 + quad;
          short8 vf = *(const short8*)&lV[row * 128 + ((chv ^ (row & 15)) << 3)];
          acc[n] = MFMA16(vf, pf, acc[n]);
        }
      }
    }
  }

  float lq = __shfl(lacc[0], l15);
  float inv = __builtin_amdgcn_rcpf(lq);
  u16* base = ctx + ((size_t)(b * SEQ + q0 + l15)) * DM + h * 64;
#pragma unroll
  for (int n = 0; n < 4; n++) {
    uint2 o;
    o.x = pack2t(acc[n][0] * inv, acc[n][1] * inv);
    o.y = pack2t(acc[n][2] * inv, acc[n][3] * inv);
    *(uint2*)(base + n * 16 + quad * 4) = o;
  }
}

extern "C" void kernel_launch(void* const* d_in, const int* in_sizes, int n_in,
                              void* d_out, int out_size, void* d_ws, size_t ws_size,
                              hipStream_t stream) {
  const float* query = (const float*)d_in[0];
  const float* key_in = (const float*)d_in[1];
  const float* value_in = (const float*)d_in[2];
  const float* Wq = (const float*)d_in[3];
  const float* bq = (const float*)d_in[4];
  const float* Wk = (const float*)d_in[5];
  const float* bk = (const float*)d_in[6];
  const float* Wv = (const float*)d_in[7];
  const float* bv = (const float*)d_in[8];
  const float* Wo = (const float*)d_in[9];
  const float* bo = (const float*)d_in[10];

  float* out = (float*)d_out;   // [B,S,DM]
  float* outK = out + 4194304;  // [B,KVH,S,64]
  float* outV = out + 5242880;  // [B,KVH,S,64]

  char* ws = (char*)d_ws;
  u16* q_act = (u16*)(ws);              // 8M  bf16 [4096,1024]
  u16* k_act = (u16*)(ws + 8388608);    // 8M
  u16* v_act = (u16*)(ws + 16777216);   // 8M
  u16* WqkvT = (u16*)(ws + 25165824);   // 3M  [1536,1024] = [Wq|Wk|Wv]^T bf16
  u16* WoT = (u16*)(ws + 28311552);     // 2M
  u16* qbf = (u16*)(ws + 30408704);     // 8M  Q bf16 [B,H,S,64], pre-scaled log2e/8
  u16* kbf = (u16*)(ws + 38797312);     // 2M  K bf16 [B,KVH,S,64]
  u16* vtb = (u16*)(ws + 40894464);     // 2M  V^T bf16 [B,KVH,64,S]
  u16* ctxb = (u16*)(ws + 42991616);    // 8M  ctx bf16 [B,S,DM]
  // high-water: 51,380,224 bytes (same as round 1)

  const float qscale = 0.125f * 1.44269504088896340736f;  // fold log2(e) -> exp2 softmax

  k_prep<<<dim3(1024, 7), 256, 0, stream>>>(query, key_in, value_in, Wq, Wk, Wv, Wo, q_act,
                                            k_act, v_act, WqkvT, WoT);
  k_proj<<<dim3(12, 32), 256, 0, stream>>>(WqkvT, q_act, k_act, v_act, bq, bk, bv, qbf,
                                           outK, kbf, outV, vtb, qscale);
  k_flash<<<dim3(32, 32), 256, 0, stream>>>(qbf, kbf, vtb, ctxb);
  k_out<<<dim3(8, 32), 256, 0, stream>>>(WoT, ctxb, bo, out);
}